// Round 17
// baseline (387.923 us; speedup 1.0000x reference)
//
#include <hip/hip_runtime.h>

#define NPTS 16384
#define CDIM 64

using bf16x8 = __attribute__((ext_vector_type(8))) short;
using s16x4  = __attribute__((ext_vector_type(4))) short;
using f32x4  = __attribute__((ext_vector_type(4))) float;
using i32x4  = __attribute__((ext_vector_type(4))) int;

static __device__ __forceinline__ float b2f(short h){
  unsigned u = ((unsigned)(unsigned short)h) << 16;
  return __builtin_bit_cast(float, u);
}
static __device__ __forceinline__ short f2b(float f){
  unsigned u = __builtin_bit_cast(unsigned, f);
  u = (u + 0x7fffu + ((u >> 16) & 1u)) >> 16;
  return (short)u;
}
// value from lane-1 within each row of 16 (DPP row_shr:1; lane0 keeps own)
static __device__ __forceinline__ int dpp_shr1_i(int x){
  return __builtin_amdgcn_update_dpp(x, x, 0x111, 0xF, 0xF, false);
}
static __device__ __forceinline__ float dpp_shr1_f(float x){
  int r = dpp_shr1_i(__builtin_bit_cast(int, x));
  return __builtin_bit_cast(float, r);
}

// ---- K1 (fused): blocks 0..255: x -> hi-bf16 + 0.5*||x||^2 ;
//                  blocks 256..287: W^T bf16 XOR-swizzled ----
__global__ __launch_bounds__(256) void k_prep(const float* __restrict__ xf,
    const float* __restrict__ Wf, short* __restrict__ xh,
    float* __restrict__ sq05, short* __restrict__ WtG){
  const int tid = threadIdx.x;
  const int b = blockIdx.x;
  if (b < 256){
    const int row = b*64 + (tid >> 2);
    const int part = tid & 3;
    const float* p = xf + row*CDIM + part*16;
    float ps = 0.f;
    bf16x8 vh0, vh1;
    #pragma unroll
    for (int e = 0; e < 8; ++e){
      float f = p[e];
      vh0[e] = f2b(f);
      ps = fmaf(f, f, ps);
    }
    #pragma unroll
    for (int e = 0; e < 8; ++e){
      float f = p[8 + e];
      vh1[e] = f2b(f);
      ps = fmaf(f, f, ps);
    }
    *(bf16x8*)(xh + row*CDIM + part*16)     = vh0;
    *(bf16x8*)(xh + row*CDIM + part*16 + 8) = vh1;
    ps += __shfl_down(ps, 2);
    ps += __shfl_down(ps, 1);
    if (part == 0) sq05[row] = 0.5f * ps;
  } else {
    const int kq = b - 256;                // k = kq*4+e
    const int n = tid;
    const int chunk = (kq >> 1) ^ (n & 15);
    s16x4 v;
    #pragma unroll
    for (int e = 0; e < 4; ++e) v[e] = f2b(Wf[(kq*4 + e)*256 + n]);
    *(s16x4*)(WtG + n*128 + chunk*8 + (kq & 1)*4) = v;
  }
}

// ---- K2: hi-bf16 distance GEMM + streaming top-16 per j-quarter ----
// (byte-identical to round-16 proven 222us version)
__global__ __launch_bounds__(256) void k_knn(const short* __restrict__ xh,
    const float* __restrict__ sq05, int* __restrict__ cand){
  __shared__ __align__(16) short Bh[2][128*72];
  __shared__ float sqt[2][128];
  const int tid = threadIdx.x, lane = tid & 63, w = tid >> 6;
  const int l15 = lane & 15, quad = lane >> 4;
  const int q = blockIdx.x & 3, ib = blockIdx.x >> 2;
  const int rb = ib*64 + w*16;
  const int jbase = q*4096;
  const int thrsrc = (lane & 48) | 15;
  const bool notl0 = (l15 != 0);

  bf16x8 ah[2];
  #pragma unroll
  for (int ks = 0; ks < 2; ++ks)
    ah[ks] = *(const bf16x8*)(xh + (rb + l15)*CDIM + ks*32 + quad*8);

  float lv[4]; int li[4]; float thr[4];
  #pragma unroll
  for (int r = 0; r < 4; ++r){
    lv[r] = __builtin_inff(); li[r] = 0; thr[r] = __builtin_inff();
  }

  #pragma unroll
  for (int g = 0; g < 4; ++g){
    int c = g*256 + tid, row = c >> 3, seg = c & 7;
    *(bf16x8*)(&Bh[0][row*72 + seg*8]) =
        *(const bf16x8*)(xh + (jbase + row)*CDIM + seg*8);
  }
  if (tid < 128) sqt[0][tid] = sq05[jbase + tid];
  __syncthreads();

  #pragma unroll 1
  for (int t = 0; t < 32; ++t){
    const int cur = t & 1;
    const int j0 = jbase + t*128;
    if (t < 31){
      const int jn = j0 + 128;
      #pragma unroll
      for (int g = 0; g < 4; ++g){
        int c = g*256 + tid, row = c >> 3, seg = c & 7;
        *(bf16x8*)(&Bh[cur^1][row*72 + seg*8]) =
            *(const bf16x8*)(xh + (jn + row)*CDIM + seg*8);
      }
      if (tid < 128) sqt[cur^1][tid] = sq05[jn + tid];
    }

    f32x4 acc[8];
    #pragma unroll
    for (int js = 0; js < 8; ++js) acc[js] = (f32x4){0.f,0.f,0.f,0.f};
    #pragma unroll
    for (int ks = 0; ks < 2; ++ks){
      #pragma unroll
      for (int js = 0; js < 8; ++js){
        bf16x8 bh = *(const bf16x8*)(&Bh[cur][(js*16 + l15)*72 + (ks*4 + quad)*8]);
        acc[js] = __builtin_amdgcn_mfma_f32_16x16x32_bf16(ah[ks], bh, acc[js], 0,0,0);
      }
    }

    #pragma unroll
    for (int js = 0; js < 8; ++js){
      float sqv = sqt[cur][js*16 + l15];
      float s4[4];
      unsigned long long bal[4];
      #pragma unroll
      for (int r = 0; r < 4; ++r){
        s4[r] = sqv - acc[js][r];
        bal[r] = __ballot(s4[r] < thr[r]);
      }
      #pragma unroll
      for (int r = 0; r < 4; ++r){
        if (bal[r]){
          unsigned qb = (unsigned)((bal[r] >> (quad*16)) & 0xffffull);
          while (qb){
            int jj = __builtin_ctz(qb); qb &= qb - 1u;
            float cv = __shfl(s4[r], quad*16 + jj);
            int   cj = j0 + js*16 + jj;
            float lp = dpp_shr1_f(lv[r]);
            int   ip = dpp_shr1_i(li[r]);
            bool c1 = (cv < lv[r]);
            bool c0 = notl0 && (cv < lp);
            float iv = c0 ? lp : cv;
            int   ii = c0 ? ip : cj;
            if (c1){ lv[r] = iv; li[r] = ii; }
          }
          thr[r] = __shfl(lv[r], thrsrc);
        }
      }
    }
    __syncthreads();
  }

  #pragma unroll
  for (int r = 0; r < 4; ++r)
    cand[(rb + quad*4 + r)*64 + q*16 + l15] = li[r];
}

// ---- K3 (fused): exact fp32 rescore + bitonic top-16 + edge-MLP ----
// grid 512 x 256: block = 32 points, wave = 8. W in 64KB LDS; MLP keeps
// 2-point shared-b-load batching.
__global__ __launch_bounds__(256) void k_mlp(const float* __restrict__ xf,
    const float* __restrict__ sq05, const short* __restrict__ WtG,
    const float* __restrict__ bfp, const int* __restrict__ cand,
    float* __restrict__ y){
  __shared__ __align__(16) short Wt[256*128];
  const int tid = threadIdx.x, lane = tid & 63, w = tid >> 6;
  const int l15 = lane & 15, quad = lane >> 4;
  for (int c = tid; c < 4096; c += 256)
    ((i32x4*)Wt)[c] = ((const i32x4*)WtG)[c];
  __syncthreads();
  const int ibase = blockIdx.x*32 + w*8;

  #pragma unroll 1
  for (int it = 0; it < 4; ++it){
    const int ia = ibase + it*2, ib2 = ia + 1;
    int nba, nbb;
    #pragma unroll
    for (int pt = 0; pt < 2; ++pt){
      const int i = pt ? ib2 : ia;
      int idx = cand[i*64 + lane] & (NPTS - 1);
      // exact rescore: d = fl(sq_i + sq_j) - 2*dot (fp32 fma dot)
      const f32x4* pi4 = (const f32x4*)(xf + i*CDIM);
      const f32x4* pj4 = (const f32x4*)(xf + idx*CDIM);
      f32x4 a4 = (f32x4){0.f,0.f,0.f,0.f};
      #pragma unroll
      for (int e = 0; e < 16; ++e){
        f32x4 va = pi4[e], vb = pj4[e];
        #pragma unroll
        for (int c = 0; c < 4; ++c) a4[c] = fmaf(va[c], vb[c], a4[c]);
      }
      float dot = (a4[0] + a4[1]) + (a4[2] + a4[3]);
      float v = fmaf(-2.f, dot, 2.f*(sq05[i] + sq05[idx]));
      if (idx == i) v = __builtin_inff();
      // bitonic sort 64 by (v, idx) ascending
      #pragma unroll
      for (int k = 2; k <= 64; k <<= 1){
        #pragma unroll
        for (int j = k >> 1; j > 0; j >>= 1){
          float pv = __shfl_xor(v, j); int pi = __shfl_xor(idx, j);
          bool dir = ((lane & k) == 0);
          bool lower = ((lane & j) == 0);
          bool pless = (pv < v) || (pv == v && pi < idx);
          bool take = (lower == dir) ? pless : !pless;
          if (take){ v = pv; idx = pi; }
        }
      }
      int nb = __shfl(idx, l15) & (NPTS - 1);
      if (pt) nbb = nb; else nba = nb;
    }

    bf16x8 afa[4], afb[4];
    {
      const float* xi = xf + ia*CDIM;
      const float* xj = xf + nba*CDIM;
      f32x4 a0 = *(const f32x4*)(xi + quad*8),      a1 = *(const f32x4*)(xi + quad*8 + 4);
      f32x4 a2 = *(const f32x4*)(xi + 32 + quad*8), a3 = *(const f32x4*)(xi + 32 + quad*8 + 4);
      f32x4 b0 = *(const f32x4*)(xj + quad*8),      b1 = *(const f32x4*)(xj + quad*8 + 4);
      f32x4 b2 = *(const f32x4*)(xj + 32 + quad*8), b3 = *(const f32x4*)(xj + 32 + quad*8 + 4);
      #pragma unroll
      for (int e = 0; e < 4; ++e){
        afa[0][e] = f2b(a0[e]); afa[0][4+e] = f2b(a1[e]);
        afa[1][e] = f2b(a2[e]); afa[1][4+e] = f2b(a3[e]);
        afa[2][e] = f2b(b0[e] - a0[e]); afa[2][4+e] = f2b(b1[e] - a1[e]);
        afa[3][e] = f2b(b2[e] - a2[e]); afa[3][4+e] = f2b(b3[e] - a3[e]);
      }
    }
    {
      const float* xi = xf + ib2*CDIM;
      const float* xj = xf + nbb*CDIM;
      f32x4 a0 = *(const f32x4*)(xi + quad*8),      a1 = *(const f32x4*)(xi + quad*8 + 4);
      f32x4 a2 = *(const f32x4*)(xi + 32 + quad*8), a3 = *(const f32x4*)(xi + 32 + quad*8 + 4);
      f32x4 b0 = *(const f32x4*)(xj + quad*8),      b1 = *(const f32x4*)(xj + quad*8 + 4);
      f32x4 b2 = *(const f32x4*)(xj + 32 + quad*8), b3 = *(const f32x4*)(xj + 32 + quad*8 + 4);
      #pragma unroll
      for (int e = 0; e < 4; ++e){
        afb[0][e] = f2b(a0[e]); afb[0][4+e] = f2b(a1[e]);
        afb[1][e] = f2b(a2[e]); afb[1][4+e] = f2b(a3[e]);
        afb[2][e] = f2b(b0[e] - a0[e]); afb[2][4+e] = f2b(b1[e] - a1[e]);
        afb[3][e] = f2b(b2[e] - a2[e]); afb[3][4+e] = f2b(b3[e] - a3[e]);
      }
    }

    #pragma unroll
    for (int half = 0; half < 2; ++half){
      f32x4 aca[8], acb[8];
      #pragma unroll
      for (int n = 0; n < 8; ++n){
        aca[n] = (f32x4){0.f,0.f,0.f,0.f};
        acb[n] = (f32x4){0.f,0.f,0.f,0.f};
      }
      #pragma unroll
      for (int ks = 0; ks < 4; ++ks){
        #pragma unroll
        for (int ntl = 0; ntl < 8; ++ntl){
          int nt = half*8 + ntl;
          int chunkS = ((ks*4 + quad) ^ l15);
          bf16x8 bfr = *(const bf16x8*)(Wt + (nt*16 + l15)*128 + chunkS*8);
          aca[ntl] = __builtin_amdgcn_mfma_f32_16x16x32_bf16(afa[ks], bfr, aca[ntl], 0,0,0);
          acb[ntl] = __builtin_amdgcn_mfma_f32_16x16x32_bf16(afb[ks], bfr, acb[ntl], 0,0,0);
        }
      }
      #pragma unroll
      for (int ntl = 0; ntl < 8; ++ntl){
        int col = (half*8 + ntl)*16 + l15;
        float bv = bfp[col];
        float ma = fmaxf(fmaxf(aca[ntl][0], aca[ntl][1]), fmaxf(aca[ntl][2], aca[ntl][3]));
        ma = fmaxf(ma, __shfl_xor(ma, 16));
        ma = fmaxf(ma, __shfl_xor(ma, 32));
        float mb = fmaxf(fmaxf(acb[ntl][0], acb[ntl][1]), fmaxf(acb[ntl][2], acb[ntl][3]));
        mb = fmaxf(mb, __shfl_xor(mb, 16));
        mb = fmaxf(mb, __shfl_xor(mb, 32));
        if (lane < 16){
          y[(ia*4  + (col & 3))*CDIM + (col >> 2)] = fmaxf(ma + bv, 0.f);
          y[(ib2*4 + (col & 3))*CDIM + (col >> 2)] = fmaxf(mb + bv, 0.f);
        }
      }
    }
  }
}

extern "C" void kernel_launch(void* const* d_in, const int* in_sizes, int n_in,
                              void* d_out, int out_size, void* d_ws, size_t ws_size,
                              hipStream_t stream){
  const float* x    = (const float*)d_in[0];
  const float* Wm   = (const float*)d_in[1];
  const float* bias = (const float*)d_in[2];
  float* y = (float*)d_out;
  char* ws = (char*)d_ws;
  short* xh   = (short*)ws;                              // 2 MB
  float* sq05 = (float*)(ws + (2 << 20));                // 64 KB
  short* WtG  = (short*)(ws + (2 << 20) + (64 << 10));   // 64 KB
  int*   cand = (int*)  (ws + (2 << 20) + (128 << 10));  // 4 MB
  (void)in_sizes; (void)n_in; (void)out_size; (void)ws_size;

  k_prep<<<288,  256, 0, stream>>>(x, Wm, xh, sq05, WtG);
  k_knn <<<1024, 256, 0, stream>>>(xh, sq05, cand);
  k_mlp <<<512,  256, 0, stream>>>(x, sq05, WtG, bias, cand, y);
}

// Round 18
// 376.153 us; speedup vs baseline: 1.0313x; 1.0313x over previous
//
#include <hip/hip_runtime.h>

#define NPTS 16384
#define CDIM 64
#define BSTR 76   // B-tile stride in shorts (152 B = 38 dwords: 4-way banks)

using bf16x8 = __attribute__((ext_vector_type(8))) short;
using s16x4  = __attribute__((ext_vector_type(4))) short;
using f32x4  = __attribute__((ext_vector_type(4))) float;
using i32x4  = __attribute__((ext_vector_type(4))) int;

static __device__ __forceinline__ float b2f(short h){
  unsigned u = ((unsigned)(unsigned short)h) << 16;
  return __builtin_bit_cast(float, u);
}
static __device__ __forceinline__ short f2b(float f){
  unsigned u = __builtin_bit_cast(unsigned, f);
  u = (u + 0x7fffu + ((u >> 16) & 1u)) >> 16;
  return (short)u;
}
// value from lane-1 within each row of 16 (DPP row_shr:1; lane0 keeps own)
static __device__ __forceinline__ int dpp_shr1_i(int x){
  return __builtin_amdgcn_update_dpp(x, x, 0x111, 0xF, 0xF, false);
}
static __device__ __forceinline__ float dpp_shr1_f(float x){
  int r = dpp_shr1_i(__builtin_bit_cast(int, x));
  return __builtin_bit_cast(float, r);
}

// ---- K1: x -> hi-bf16 plane + 0.5*||x||^2 ----
__global__ __launch_bounds__(256) void k_prep(const float* __restrict__ xf,
    short* __restrict__ xh, float* __restrict__ sq05){
  const int tid = threadIdx.x;
  const int row = blockIdx.x*64 + (tid >> 2);
  const int part = tid & 3;
  const float* p = xf + row*CDIM + part*16;
  float ps = 0.f;
  bf16x8 vh0, vh1;
  #pragma unroll
  for (int e = 0; e < 8; ++e){
    float f = p[e];
    vh0[e] = f2b(f);
    ps = fmaf(f, f, ps);
  }
  #pragma unroll
  for (int e = 0; e < 8; ++e){
    float f = p[8 + e];
    vh1[e] = f2b(f);
    ps = fmaf(f, f, ps);
  }
  *(bf16x8*)(xh + row*CDIM + part*16)     = vh0;
  *(bf16x8*)(xh + row*CDIM + part*16 + 8) = vh1;
  ps += __shfl_down(ps, 2);
  ps += __shfl_down(ps, 1);
  if (part == 0) sq05[row] = 0.5f * ps;
}

// ---- K2: W^T bf16, XOR-swizzled (layout k_mlp reads) ----
__global__ __launch_bounds__(256) void k_wprep(const float* __restrict__ Wf,
    short* __restrict__ WtG){
  const int n = threadIdx.x;
  const int kq = blockIdx.x;               // k = kq*4+e
  const int chunk = (kq >> 1) ^ (n & 15);
  s16x4 v;
  #pragma unroll
  for (int e = 0; e < 4; ++e) v[e] = f2b(Wf[(kq*4 + e)*256 + n]);
  *(s16x4*)(WtG + n*128 + chunk*8 + (kq & 1)*4) = v;
}

// ---- K3: hi-bf16 distance GEMM + streaming top-16 per j-quarter ----
// Round-16 structure; only change: tile stride 72 -> 76 (bank-conflict fix).
__global__ __launch_bounds__(256) void k_knn(const short* __restrict__ xh,
    const float* __restrict__ sq05, int* __restrict__ cand){
  __shared__ __align__(16) short Bh[2][128*BSTR];
  __shared__ float sqt[2][128];
  const int tid = threadIdx.x, lane = tid & 63, w = tid >> 6;
  const int l15 = lane & 15, quad = lane >> 4;
  const int q = blockIdx.x & 3, ib = blockIdx.x >> 2;
  const int rb = ib*64 + w*16;
  const int jbase = q*4096;
  const int thrsrc = (lane & 48) | 15;
  const bool notl0 = (l15 != 0);

  bf16x8 ah[2];
  #pragma unroll
  for (int ks = 0; ks < 2; ++ks)
    ah[ks] = *(const bf16x8*)(xh + (rb + l15)*CDIM + ks*32 + quad*8);

  float lv[4]; int li[4]; float thr[4];
  #pragma unroll
  for (int r = 0; r < 4; ++r){
    lv[r] = __builtin_inff(); li[r] = 0; thr[r] = __builtin_inff();
  }

  #pragma unroll
  for (int g = 0; g < 4; ++g){
    int c = g*256 + tid, row = c >> 3, seg = c & 7;
    *(bf16x8*)(&Bh[0][row*BSTR + seg*8]) =
        *(const bf16x8*)(xh + (jbase + row)*CDIM + seg*8);
  }
  if (tid < 128) sqt[0][tid] = sq05[jbase + tid];
  __syncthreads();

  #pragma unroll 1
  for (int t = 0; t < 32; ++t){
    const int cur = t & 1;
    const int j0 = jbase + t*128;
    if (t < 31){
      const int jn = j0 + 128;
      #pragma unroll
      for (int g = 0; g < 4; ++g){
        int c = g*256 + tid, row = c >> 3, seg = c & 7;
        *(bf16x8*)(&Bh[cur^1][row*BSTR + seg*8]) =
            *(const bf16x8*)(xh + (jn + row)*CDIM + seg*8);
      }
      if (tid < 128) sqt[cur^1][tid] = sq05[jn + tid];
    }

    f32x4 acc[8];
    #pragma unroll
    for (int js = 0; js < 8; ++js) acc[js] = (f32x4){0.f,0.f,0.f,0.f};
    #pragma unroll
    for (int ks = 0; ks < 2; ++ks){
      #pragma unroll
      for (int js = 0; js < 8; ++js){
        bf16x8 bh = *(const bf16x8*)(&Bh[cur][(js*16 + l15)*BSTR + (ks*4 + quad)*8]);
        acc[js] = __builtin_amdgcn_mfma_f32_16x16x32_bf16(ah[ks], bh, acc[js], 0,0,0);
      }
    }

    #pragma unroll
    for (int js = 0; js < 8; ++js){
      float sqv = sqt[cur][js*16 + l15];
      float s4[4];
      unsigned long long bal[4];
      #pragma unroll
      for (int r = 0; r < 4; ++r){
        s4[r] = sqv - acc[js][r];
        bal[r] = __ballot(s4[r] < thr[r]);
      }
      #pragma unroll
      for (int r = 0; r < 4; ++r){
        if (bal[r]){
          unsigned qb = (unsigned)((bal[r] >> (quad*16)) & 0xffffull);
          while (qb){
            int jj = __builtin_ctz(qb); qb &= qb - 1u;
            float cv = __shfl(s4[r], quad*16 + jj);
            int   cj = j0 + js*16 + jj;
            float lp = dpp_shr1_f(lv[r]);
            int   ip = dpp_shr1_i(li[r]);
            bool c1 = (cv < lv[r]);
            bool c0 = notl0 && (cv < lp);
            float iv = c0 ? lp : cv;
            int   ii = c0 ? ip : cj;
            if (c1){ lv[r] = iv; li[r] = ii; }
          }
          thr[r] = __shfl(lv[r], thrsrc);
        }
      }
    }
    __syncthreads();
  }

  #pragma unroll
  for (int r = 0; r < 4; ++r)
    cand[(rb + quad*4 + r)*64 + q*16 + l15] = li[r];
}

// ---- K4: exact fp32 rescore of 64 candidates + bitonic top-16 ----
__global__ __launch_bounds__(256) void k_sel(const float* __restrict__ xf,
    const float* __restrict__ sq05, const int* __restrict__ cand,
    int* __restrict__ nbr){
  const int lane = threadIdx.x & 63, w = threadIdx.x >> 6;
  const int i = blockIdx.x*4 + w;
  int idx = cand[i*64 + lane] & (NPTS - 1);

  const f32x4* pi4 = (const f32x4*)(xf + i*CDIM);
  const f32x4* pj4 = (const f32x4*)(xf + idx*CDIM);
  f32x4 a4 = (f32x4){0.f,0.f,0.f,0.f};
  #pragma unroll
  for (int e = 0; e < 16; ++e){
    f32x4 va = pi4[e], vb = pj4[e];
    #pragma unroll
    for (int c = 0; c < 4; ++c) a4[c] = fmaf(va[c], vb[c], a4[c]);
  }
  float dot = (a4[0] + a4[1]) + (a4[2] + a4[3]);
  float v = fmaf(-2.f, dot, 2.f*(sq05[i] + sq05[idx]));
  if (idx == i) v = __builtin_inff();

  #pragma unroll
  for (int k = 2; k <= 64; k <<= 1){
    #pragma unroll
    for (int j = k >> 1; j > 0; j >>= 1){
      float pv = __shfl_xor(v, j); int pi = __shfl_xor(idx, j);
      bool dir = ((lane & k) == 0);
      bool lower = ((lane & j) == 0);
      bool pless = (pv < v) || (pv == v && pi < idx);
      bool take = (lower == dir) ? pless : !pless;
      if (take){ v = pv; idx = pi; }
    }
  }
  if (lane < 16) nbr[i*16 + lane] = idx;
}

// ---- K5: edge-MLP + maxpool + permuted store; 2 points share b-loads ----
__global__ __launch_bounds__(256) void k_mlp(const float* __restrict__ xf,
    const short* __restrict__ WtG, const float* __restrict__ bfp,
    const int* __restrict__ nbr, float* __restrict__ y){
  __shared__ __align__(16) short Wt[256*128];
  const int tid = threadIdx.x, lane = tid & 63, w = tid >> 6;
  const int l15 = lane & 15, quad = lane >> 4;
  for (int c = tid; c < 4096; c += 256)
    ((i32x4*)Wt)[c] = ((const i32x4*)WtG)[c];
  __syncthreads();
  const int ibase = blockIdx.x*32 + w*8;

  #pragma unroll 1
  for (int it = 0; it < 4; ++it){
    const int ia = ibase + it*2, ib2 = ia + 1;
    const int nba = nbr[ia*16  + l15] & (NPTS - 1);
    const int nbb = nbr[ib2*16 + l15] & (NPTS - 1);
    bf16x8 afa[4], afb[4];
    {
      const float* xi = xf + ia*CDIM;
      const float* xj = xf + nba*CDIM;
      f32x4 a0 = *(const f32x4*)(xi + quad*8),      a1 = *(const f32x4*)(xi + quad*8 + 4);
      f32x4 a2 = *(const f32x4*)(xi + 32 + quad*8), a3 = *(const f32x4*)(xi + 32 + quad*8 + 4);
      f32x4 b0 = *(const f32x4*)(xj + quad*8),      b1 = *(const f32x4*)(xj + quad*8 + 4);
      f32x4 b2 = *(const f32x4*)(xj + 32 + quad*8), b3 = *(const f32x4*)(xj + 32 + quad*8 + 4);
      #pragma unroll
      for (int e = 0; e < 4; ++e){
        afa[0][e] = f2b(a0[e]); afa[0][4+e] = f2b(a1[e]);
        afa[1][e] = f2b(a2[e]); afa[1][4+e] = f2b(a3[e]);
        afa[2][e] = f2b(b0[e] - a0[e]); afa[2][4+e] = f2b(b1[e] - a1[e]);
        afa[3][e] = f2b(b2[e] - a2[e]); afa[3][4+e] = f2b(b3[e] - a3[e]);
      }
    }
    {
      const float* xi = xf + ib2*CDIM;
      const float* xj = xf + nbb*CDIM;
      f32x4 a0 = *(const f32x4*)(xi + quad*8),      a1 = *(const f32x4*)(xi + quad*8 + 4);
      f32x4 a2 = *(const f32x4*)(xi + 32 + quad*8), a3 = *(const f32x4*)(xi + 32 + quad*8 + 4);
      f32x4 b0 = *(const f32x4*)(xj + quad*8),      b1 = *(const f32x4*)(xj + quad*8 + 4);
      f32x4 b2 = *(const f32x4*)(xj + 32 + quad*8), b3 = *(const f32x4*)(xj + 32 + quad*8 + 4);
      #pragma unroll
      for (int e = 0; e < 4; ++e){
        afb[0][e] = f2b(a0[e]); afb[0][4+e] = f2b(a1[e]);
        afb[1][e] = f2b(a2[e]); afb[1][4+e] = f2b(a3[e]);
        afb[2][e] = f2b(b0[e] - a0[e]); afb[2][4+e] = f2b(b1[e] - a1[e]);
        afb[3][e] = f2b(b2[e] - a2[e]); afb[3][4+e] = f2b(b3[e] - a3[e]);
      }
    }

    #pragma unroll
    for (int half = 0; half < 2; ++half){
      f32x4 aca[8], acb[8];
      #pragma unroll
      for (int n = 0; n < 8; ++n){
        aca[n] = (f32x4){0.f,0.f,0.f,0.f};
        acb[n] = (f32x4){0.f,0.f,0.f,0.f};
      }
      #pragma unroll
      for (int ks = 0; ks < 4; ++ks){
        #pragma unroll
        for (int ntl = 0; ntl < 8; ++ntl){
          int nt = half*8 + ntl;
          int chunkS = ((ks*4 + quad) ^ l15);
          bf16x8 bfr = *(const bf16x8*)(Wt + (nt*16 + l15)*128 + chunkS*8);
          aca[ntl] = __builtin_amdgcn_mfma_f32_16x16x32_bf16(afa[ks], bfr, aca[ntl], 0,0,0);
          acb[ntl] = __builtin_amdgcn_mfma_f32_16x16x32_bf16(afb[ks], bfr, acb[ntl], 0,0,0);
        }
      }
      #pragma unroll
      for (int ntl = 0; ntl < 8; ++ntl){
        int col = (half*8 + ntl)*16 + l15;
        float bv = bfp[col];
        float ma = fmaxf(fmaxf(aca[ntl][0], aca[ntl][1]), fmaxf(aca[ntl][2], aca[ntl][3]));
        ma = fmaxf(ma, __shfl_xor(ma, 16));
        ma = fmaxf(ma, __shfl_xor(ma, 32));
        float mb = fmaxf(fmaxf(acb[ntl][0], acb[ntl][1]), fmaxf(acb[ntl][2], acb[ntl][3]));
        mb = fmaxf(mb, __shfl_xor(mb, 16));
        mb = fmaxf(mb, __shfl_xor(mb, 32));
        if (lane < 16){
          y[(ia*4  + (col & 3))*CDIM + (col >> 2)] = fmaxf(ma + bv, 0.f);
          y[(ib2*4 + (col & 3))*CDIM + (col >> 2)] = fmaxf(mb + bv, 0.f);
        }
      }
    }
  }
}

extern "C" void kernel_launch(void* const* d_in, const int* in_sizes, int n_in,
                              void* d_out, int out_size, void* d_ws, size_t ws_size,
                              hipStream_t stream){
  const float* x    = (const float*)d_in[0];
  const float* Wm   = (const float*)d_in[1];
  const float* bias = (const float*)d_in[2];
  float* y = (float*)d_out;
  char* ws = (char*)d_ws;
  short* xh   = (short*)ws;                              // 2 MB
  float* sq05 = (float*)(ws + (2 << 20));                // 64 KB
  short* WtG  = (short*)(ws + (2 << 20) + (64 << 10));   // 64 KB
  int*   cand = (int*)  (ws + (2 << 20) + (128 << 10));  // 4 MB
  int*   nbr  = (int*)  (ws + (6 << 20) + (128 << 10));  // 1 MB
  (void)in_sizes; (void)n_in; (void)out_size; (void)ws_size;

  k_prep <<<256,  256, 0, stream>>>(x, xh, sq05);
  k_wprep<<<32,   256, 0, stream>>>(Wm, WtG);
  k_knn  <<<1024, 256, 0, stream>>>(xh, sq05, cand);
  k_sel  <<<4096, 256, 0, stream>>>(x, sq05, cand, nbr);
  k_mlp  <<<512,  256, 0, stream>>>(x, WtG, bias, nbr, y);
}